// Round 6
// baseline (4016.889 us; speedup 1.0000x reference)
//
#include <hip/hip_runtime.h>
#include <math.h>

// Problem constants: T=64, B=1024, H=512, V=512
constexpr int T_STEPS = 64;
constexpr int B_SZ = 1024;
constexpr int H_SZ = 512;
constexpr int V_SZ = 512;
constexpr int G_SZ = 4 * H_SZ; // 2048
constexpr int NBLK = 256;      // 1 block per CU; all co-resident (512 thr, ~1KB LDS)

typedef _Float16 half8 __attribute__((ext_vector_type(8)));
typedef _Float16 half4 __attribute__((ext_vector_type(4)));
typedef float f32x4 __attribute__((ext_vector_type(4)));

__device__ __forceinline__ float4 ld4(const float* p) {
    return *reinterpret_cast<const float4*>(p);
}
__device__ __forceinline__ void st4(float* p, float4 v) {
    *reinterpret_cast<float4*>(p) = v;
}
__device__ __forceinline__ float sigf(float x) { return 1.f / (1.f + expf(-x)); }

// packed argmax word: high 32 = orderable float key, low 32 = (511 - col)
__device__ __forceinline__ unsigned long long pack_vc(float v, int col) {
    unsigned u = __float_as_uint(v);
    unsigned key = (u & 0x80000000u) ? ~u : (u | 0x80000000u);
    return ((unsigned long long)key << 32) | (unsigned)(511 - col);
}

// device-scope (MALL) accesses — ONLY for tok values and the step counter
__device__ __forceinline__ unsigned long long ld_u64_coh(const unsigned long long* p) {
    return __hip_atomic_load(p, __ATOMIC_RELAXED, __HIP_MEMORY_SCOPE_AGENT);
}

// ---------------------------------------------------------------------------
// fp32 -> (hi fp16, lo fp16) split: x ~= hi + lo/2048
// ---------------------------------------------------------------------------
__global__ __launch_bounds__(256) void cvt_pair(
    const float* __restrict__ x, _Float16* __restrict__ hi,
    _Float16* __restrict__ lo)
{
    const int i4 = blockIdx.x * 256 + threadIdx.x;
    const float4 v = ld4(x + (size_t)i4 * 4);
    half4 h, l;
    const float h0 = (float)(_Float16)v.x; h[0] = (_Float16)v.x; l[0] = (_Float16)((v.x - h0) * 2048.f);
    const float h1 = (float)(_Float16)v.y; h[1] = (_Float16)v.y; l[1] = (_Float16)((v.y - h1) * 2048.f);
    const float h2 = (float)(_Float16)v.z; h[2] = (_Float16)v.z; l[2] = (_Float16)((v.z - h2) * 2048.f);
    const float h3 = (float)(_Float16)v.w; h[3] = (_Float16)v.w; l[3] = (_Float16)((v.w - h3) * 2048.f);
    *reinterpret_cast<half4*>(hi + (size_t)i4 * 4) = h;
    *reinterpret_cast<half4*>(lo + (size_t)i4 * 4) = l;
}

// ---------------------------------------------------------------------------
// fp32 tiled NT GEMM — used once for E_gates = emb @ W_ih^T + (b_ih+b_hh)
// ---------------------------------------------------------------------------
__global__ __launch_bounds__(256) void gemm_nt_f32(
    const float* __restrict__ A, const float* __restrict__ Bw,
    float* __restrict__ C, int M, int N, int K,
    const float* __restrict__ bias1, const float* __restrict__ bias2)
{
    constexpr int BK = 16;
    __shared__ __align__(16) float As[BK][64];
    __shared__ __align__(16) float Bs[BK][64];
    const int tid = threadIdx.x;
    const int tx = tid % 16, ty = tid / 16;
    const int m0 = blockIdx.y * 64, n0 = blockIdx.x * 64;
    const int lr = tid / 4, lc = (tid % 4) * 4;
    float acc[4][4] = {};
    for (int k0 = 0; k0 < K; k0 += BK) {
        const float4 av = ld4(&A[(size_t)(m0 + lr) * K + (k0 + lc)]);
        const float4 bv = ld4(&Bw[(size_t)(n0 + lr) * K + (k0 + lc)]);
        __syncthreads();
        As[lc + 0][lr] = av.x; As[lc + 1][lr] = av.y; As[lc + 2][lr] = av.z; As[lc + 3][lr] = av.w;
        Bs[lc + 0][lr] = bv.x; Bs[lc + 1][lr] = bv.y; Bs[lc + 2][lr] = bv.z; Bs[lc + 3][lr] = bv.w;
        __syncthreads();
#pragma unroll
        for (int k = 0; k < BK; ++k) {
            const float4 a4 = ld4(&As[k][ty * 4]);
            const float4 b4 = ld4(&Bs[k][tx * 4]);
            const float ar[4] = {a4.x, a4.y, a4.z, a4.w};
            const float br[4] = {b4.x, b4.y, b4.z, b4.w};
#pragma unroll
            for (int i = 0; i < 4; ++i)
#pragma unroll
                for (int j = 0; j < 4; ++j)
                    acc[i][j] = fmaf(ar[i], br[j], acc[i][j]);
        }
    }
    const int nc = n0 + tx * 4;
    const float4 b1 = ld4(&bias1[nc]);
    const float4 b2 = ld4(&bias2[nc]);
#pragma unroll
    for (int i = 0; i < 4; ++i) {
        const int m = m0 + ty * 4 + i;
        float4 v;
        v.x = acc[i][0] + b1.x + b2.x; v.y = acc[i][1] + b1.y + b2.y;
        v.z = acc[i][2] + b1.z + b2.z; v.w = acc[i][3] + b1.w + b2.w;
        st4(&C[(size_t)m * N + nc], v);
    }
}

// ---------------------------------------------------------------------------
// init: tokbuf has 65 step-slots of 1024 packed words; slot 0 preset to SOS
// (packed low32 = 511 -> token 0). ctr[0..64] zeroed.
// ---------------------------------------------------------------------------
__global__ __launch_bounds__(512) void init_buf(
    unsigned long long* __restrict__ tok, unsigned* __restrict__ ctr)
{
    const int i = blockIdx.x * 512 + threadIdx.x; // 0 .. 65*1024-1
    tok[i] = (i < 1024) ? 511ULL : 0ULL;
    if (i <= T_STEPS) ctr[i] = 0u;
}

// ---------------------------------------------------------------------------
// Fused per-step kernel (launched 65x). Kernel t:
//   A-part (t<64): gates GEMM for step t — 128 batches x 64 gate-cols/block
//     (bid&31 -> 16 h-cols x 4 gates, bid>>5 -> batch slice). Plain loads:
//     h(t) from kernel-boundary-coherent L2, W_hh streamed from L2.
//   B-part (t>0): logits(t-1)+argmax -> tok(t) via device atomicMax; then
//     per-block completion tick on ctr[t] (vmcnt-drained, wave 0).
//   cell (t<64): spin ctr[t]==256 (slack-free: all blocks did A+B first),
//     sc1 tok read, Eg gather, LSTM cell in registers, plain h/c stores.
// Cross-step coherence = kernel boundaries (no grid barriers, no sc1 bulk).
// Numerics: MFMA k-order and cell math identical to r0-r5 (absmax-preserving).
// ---------------------------------------------------------------------------
__global__ __launch_bounds__(512) void decode_step(
    const int t,
    const _Float16* __restrict__ Whh_hi, const _Float16* __restrict__ Whh_lo,
    const _Float16* __restrict__ Wout_hi, const _Float16* __restrict__ Wout_lo,
    const float* __restrict__ Eg, const float* __restrict__ b_out,
    const _Float16* __restrict__ Ah, const _Float16* __restrict__ Al,  // h(t)
    _Float16* __restrict__ Nh, _Float16* __restrict__ Nl,              // h(t+1)
    float* __restrict__ cbuf, float* __restrict__ out,                 // logits(t-1)
    unsigned long long* __restrict__ tok_t, unsigned* __restrict__ ctr_t)
{
    __shared__ unsigned long long sbest[128];

    const int tid = threadIdx.x;
    const int wave = tid >> 6, lane = tid & 63;
    const int lm = lane & 15, kq = lane >> 4;
    const int bid = blockIdx.x;

    // ---- A geometry ----
    const int hc0 = (bid & 31) * 16;
    const int b0 = (bid >> 5) * 128;
    const size_t aOffA = (size_t)(b0 + wave * 16 + lm) * 512 + kq * 8;
    const int bbase = b0 + wave * 16 + kq * 4;
    const int hc = hc0 + lm;

    f32x4 aH[4] = {{0.f, 0.f, 0.f, 0.f}, {0.f, 0.f, 0.f, 0.f},
                   {0.f, 0.f, 0.f, 0.f}, {0.f, 0.f, 0.f, 0.f}};
    f32x4 aC[4] = {{0.f, 0.f, 0.f, 0.f}, {0.f, 0.f, 0.f, 0.f},
                   {0.f, 0.f, 0.f, 0.f}, {0.f, 0.f, 0.f, 0.f}};

    // ================= A-part: gates GEMM (no tok needed yet) =================
    if (t < T_STEPS) {
        const _Float16* wh[4];
        const _Float16* wl[4];
#pragma unroll
        for (int gn = 0; gn < 4; ++gn) {
            const size_t off = (size_t)(gn * 512 + hc0 + lm) * 512 + kq * 8;
            wh[gn] = Whh_hi + off;
            wl[gn] = Whh_lo + off;
        }
#pragma unroll
        for (int it = 0; it < 16; ++it) {
            const int k0 = it * 32;
            const half8 ah = *(const half8*)(Ah + aOffA + k0);
            const half8 al = *(const half8*)(Al + aOffA + k0);
            half8 bh[4], bl[4];
#pragma unroll
            for (int gn = 0; gn < 4; ++gn) {
                bh[gn] = *(const half8*)(wh[gn] + k0);
                bl[gn] = *(const half8*)(wl[gn] + k0);
            }
#pragma unroll
            for (int gn = 0; gn < 4; ++gn)
                aH[gn] = __builtin_amdgcn_mfma_f32_16x16x32_f16(ah, bh[gn], aH[gn], 0, 0, 0);
#pragma unroll
            for (int gn = 0; gn < 4; ++gn)
                aC[gn] = __builtin_amdgcn_mfma_f32_16x16x32_f16(ah, bl[gn], aC[gn], 0, 0, 0);
#pragma unroll
            for (int gn = 0; gn < 4; ++gn)
                aC[gn] = __builtin_amdgcn_mfma_f32_16x16x32_f16(al, bh[gn], aC[gn], 0, 0, 0);
        }
    }

    // ================= B-part: logits(t-1) + argmax -> tok(t) =================
    if (t > 0) {
        const int m0 = (bid >> 2) * 16;
        const int n0v = (bid & 3) * 128;
        const int colB = n0v + wave * 16 + lm;
        const size_t aOffB = (size_t)(m0 + lm) * 512 + kq * 8;
        const size_t bOffB = (size_t)colB * 512 + kq * 8;

        f32x4 aHb = {0.f, 0.f, 0.f, 0.f};
        f32x4 aCb = {0.f, 0.f, 0.f, 0.f};
#pragma unroll
        for (int it = 0; it < 16; ++it) {
            const int k0 = it * 32;
            const half8 ah = *(const half8*)(Ah + aOffB + k0);
            const half8 al = *(const half8*)(Al + aOffB + k0);
            const half8 bh = *(const half8*)(Wout_hi + bOffB + k0);
            const half8 bl = *(const half8*)(Wout_lo + bOffB + k0);
            aHb = __builtin_amdgcn_mfma_f32_16x16x32_f16(ah, bh, aHb, 0, 0, 0);
            aCb = __builtin_amdgcn_mfma_f32_16x16x32_f16(ah, bl, aCb, 0, 0, 0);
            aCb = __builtin_amdgcn_mfma_f32_16x16x32_f16(al, bh, aCb, 0, 0, 0);
        }

        const float bo = b_out[colB];
        unsigned long long best[4];
#pragma unroll
        for (int r = 0; r < 4; ++r) {
            const float v = aHb[r] + aCb[r] * (1.f / 2048.f) + bo;
            const int row = m0 + kq * 4 + r;
            __builtin_nontemporal_store(v, &out[(size_t)row * V_SZ + colB]);
            best[r] = pack_vc(v, colB);
        }
#pragma unroll
        for (int r = 0; r < 4; ++r) {
#pragma unroll
            for (int off = 1; off < 16; off <<= 1) {
                const unsigned long long o = __shfl_xor(best[r], off);
                if (o > best[r]) best[r] = o;
            }
        }
        if (lm == 0) {
#pragma unroll
            for (int r = 0; r < 4; ++r)
                sbest[wave * 16 + kq * 4 + r] = best[r];
        }
        __syncthreads();
        if (tid < 16) {
            unsigned long long m = sbest[tid];
#pragma unroll
            for (int w = 1; w < 8; ++w)
                if (sbest[w * 16 + tid] > m) m = sbest[w * 16 + tid];
            atomicMax(&tok_t[m0 + tid], m);
        }
        // wave 0: drain this wave's atomicMax ops, then tick the step counter
        if (wave == 0) {
            asm volatile("s_waitcnt vmcnt(0)" ::: "memory");
            if (tid == 0)
                __hip_atomic_fetch_add(ctr_t, 1u, __ATOMIC_RELAXED,
                                       __HIP_MEMORY_SCOPE_AGENT);
        }
    }

    // ================= cell: needs tok(t) complete across all blocks ==========
    if (t < T_STEPS) {
        if (t > 0) {
            if (tid == 0) {
                while (__hip_atomic_load(ctr_t, __ATOMIC_RELAXED,
                                         __HIP_MEMORY_SCOPE_AGENT) < (unsigned)NBLK) {
                    __builtin_amdgcn_s_sleep(4);
                }
            }
            __syncthreads();
        }
#pragma unroll
        for (int r = 0; r < 4; ++r) {
            const int bb = bbase + r;
            const unsigned long long pk = ld_u64_coh(&tok_t[bb]);
            const int tk = 511 - (int)(unsigned)(pk & 0xFFFFFFFFu);
            const float* eg = Eg + (size_t)tk * G_SZ + hc;
            const float iv = aH[0][r] + aC[0][r] * (1.f / 2048.f) + eg[0];
            const float fv = aH[1][r] + aC[1][r] * (1.f / 2048.f) + eg[512];
            const float gv = aH[2][r] + aC[2][r] * (1.f / 2048.f) + eg[1024];
            const float ov = aH[3][r] + aC[3][r] * (1.f / 2048.f) + eg[1536];
            const size_t ci = (size_t)bb * 512 + hc;
            const float cc = cbuf[ci];
            const float cn = sigf(fv) * cc + sigf(iv) * tanhf(gv);
            const float hn = sigf(ov) * tanhf(cn);
            cbuf[ci] = cn;
            const _Float16 hi = (_Float16)hn;
            const _Float16 lo = (_Float16)((hn - (float)hi) * 2048.f);
            Nh[ci] = hi;
            Nl[ci] = lo;
        }
    }
}

// ---------------------------------------------------------------------------
extern "C" void kernel_launch(void* const* d_in, const int* in_sizes, int n_in,
                              void* d_out, int out_size, void* d_ws, size_t ws_size,
                              hipStream_t stream)
{
    const float* enc_h = (const float*)d_in[2];
    const float* enc_c = (const float*)d_in[3];
    const float* emb   = (const float*)d_in[4];
    const float* W_ih  = (const float*)d_in[5];
    const float* W_hh  = (const float*)d_in[6];
    const float* b_ih  = (const float*)d_in[7];
    const float* b_hh  = (const float*)d_in[8];
    const float* W_out = (const float*)d_in[9];
    const float* b_out = (const float*)d_in[10];
    float* out = (float*)d_out;

    // workspace layout
    char* ws = (char*)d_ws;
    _Float16* Whh_hi  = (_Float16*)(ws);                          // 2 MB
    _Float16* Whh_lo  = (_Float16*)(ws + (2u << 20));             // 2 MB
    _Float16* Wout_hi = (_Float16*)(ws + (4u << 20));             // 0.5 MB
    _Float16* Wout_lo = (_Float16*)(ws + (4u << 20) + (512u << 10));
    _Float16* Hhi0 = (_Float16*)(ws + (5u << 20));
    _Float16* Hlo0 = (_Float16*)(ws + (6u << 20));
    _Float16* Hhi1 = (_Float16*)(ws + (7u << 20));
    _Float16* Hlo1 = (_Float16*)(ws + (8u << 20));
    float* cbuf = (float*)(ws + (9u << 20));                      // 2 MB
    float* Eg   = (float*)(ws + (11u << 20));                     // 4 MB
    unsigned long long* tokbuf = (unsigned long long*)(ws + (15u << 20)); // 65*8 KB
    unsigned* ctr = (unsigned*)(ws + (15u << 20) + (544u << 10)); // 65 u32

    const dim3 blk256(256);

    // one-time conversions + init
    cvt_pair<<<(G_SZ * H_SZ) / 1024, blk256, 0, stream>>>(W_hh, Whh_hi, Whh_lo);
    cvt_pair<<<(V_SZ * H_SZ) / 1024, blk256, 0, stream>>>(W_out, Wout_hi, Wout_lo);
    cvt_pair<<<(B_SZ * H_SZ) / 1024, blk256, 0, stream>>>(enc_h, Hhi0, Hlo0);
    hipMemcpyAsync(cbuf, enc_c, (size_t)B_SZ * H_SZ * 4, hipMemcpyDeviceToDevice, stream);
    init_buf<<<(65 * 1024) / 512, dim3(512), 0, stream>>>(tokbuf, ctr);

    // E_gates = emb @ W_ih^T + (b_ih + b_hh)   [V x 4H], fp32, once
    gemm_nt_f32<<<dim3(G_SZ / 64, V_SZ / 64), blk256, 0, stream>>>(
        emb, W_ih, Eg, V_SZ, G_SZ, H_SZ, b_ih, b_hh);

    // 65 fused step kernels: kernel t = logits(t-1)+argmax + gates/cell(t)
    for (int t = 0; t <= T_STEPS; ++t) {
        const int cur = t & 1;
        decode_step<<<NBLK, dim3(512), 0, stream>>>(
            t, Whh_hi, Whh_lo, Wout_hi, Wout_lo, Eg, b_out,
            cur ? Hhi1 : Hhi0, cur ? Hlo1 : Hlo0,
            cur ? Hhi0 : Hhi1, cur ? Hlo0 : Hlo1,
            cbuf,
            (t > 0) ? out + (size_t)(t - 1) * B_SZ * V_SZ : out,
            tokbuf + (size_t)t * B_SZ, ctr + t);
    }
}

// Round 7
// 2171.404 us; speedup vs baseline: 1.8499x; 1.8499x over previous
//
#include <hip/hip_runtime.h>
#include <math.h>

// Problem constants: T=64, B=1024, H=512, V=512
constexpr int T_STEPS = 64;
constexpr int B_SZ = 1024;
constexpr int H_SZ = 512;
constexpr int V_SZ = 512;
constexpr int G_SZ = 4 * H_SZ; // 2048
constexpr int NBLK = 256;      // 1 block per CU (129KB LDS); all co-resident

typedef _Float16 half8 __attribute__((ext_vector_type(8)));
typedef _Float16 half4 __attribute__((ext_vector_type(4)));
typedef float f32x4 __attribute__((ext_vector_type(4)));

__device__ __forceinline__ float4 ld4(const float* p) {
    return *reinterpret_cast<const float4*>(p);
}
__device__ __forceinline__ float sigf(float x) { return 1.f / (1.f + expf(-x)); }

// packed argmax word: high 32 = orderable float key, low 32 = (511 - col)
__device__ __forceinline__ unsigned long long pack_vc(float v, int col) {
    unsigned u = __float_as_uint(v);
    unsigned key = (u & 0x80000000u) ? ~u : (u | 0x80000000u);
    return ((unsigned long long)key << 32) | (unsigned)(511 - col);
}

// device-scope (MALL) accesses — ONLY for tok values and step counters
__device__ __forceinline__ unsigned long long ld_u64_coh(const unsigned long long* p) {
    return __hip_atomic_load(p, __ATOMIC_RELAXED, __HIP_MEMORY_SCOPE_AGENT);
}

// async global->LDS DMA, 16B/lane, wave-linear LDS destination
#define GLDS(g, l) __builtin_amdgcn_global_load_lds(                      \
    (const __attribute__((address_space(1))) void*)(g),                   \
    (__attribute__((address_space(3))) void*)(l), 16, 0, 0)

// ---------------------------------------------------------------------------
// fp32 -> (hi fp16, lo fp16) split: x ~= hi + lo/2048
// ---------------------------------------------------------------------------
__global__ __launch_bounds__(256) void cvt_pair(
    const float* __restrict__ x, _Float16* __restrict__ hi,
    _Float16* __restrict__ lo)
{
    const int i4 = blockIdx.x * 256 + threadIdx.x;
    const float4 v = ld4(x + (size_t)i4 * 4);
    half4 h, l;
    const float h0 = (float)(_Float16)v.x; h[0] = (_Float16)v.x; l[0] = (_Float16)((v.x - h0) * 2048.f);
    const float h1 = (float)(_Float16)v.y; h[1] = (_Float16)v.y; l[1] = (_Float16)((v.y - h1) * 2048.f);
    const float h2 = (float)(_Float16)v.z; h[2] = (_Float16)v.z; l[2] = (_Float16)((v.z - h2) * 2048.f);
    const float h3 = (float)(_Float16)v.w; h[3] = (_Float16)v.w; l[3] = (_Float16)((v.w - h3) * 2048.f);
    *reinterpret_cast<half4*>(hi + (size_t)i4 * 4) = h;
    *reinterpret_cast<half4*>(lo + (size_t)i4 * 4) = l;
}

// ---------------------------------------------------------------------------
// fp32 tiled NT GEMM — used once for E_gates = emb @ W_ih^T + (b_ih+b_hh)
// ---------------------------------------------------------------------------
__global__ __launch_bounds__(256) void gemm_nt_f32(
    const float* __restrict__ A, const float* __restrict__ Bw,
    float* __restrict__ C, int M, int N, int K,
    const float* __restrict__ bias1, const float* __restrict__ bias2)
{
    constexpr int BK = 16;
    __shared__ __align__(16) float As[BK][64];
    __shared__ __align__(16) float Bs[BK][64];
    const int tid = threadIdx.x;
    const int tx = tid % 16, ty = tid / 16;
    const int m0 = blockIdx.y * 64, n0 = blockIdx.x * 64;
    const int lr = tid / 4, lc = (tid % 4) * 4;
    float acc[4][4] = {};
    for (int k0 = 0; k0 < K; k0 += BK) {
        const float4 av = ld4(&A[(size_t)(m0 + lr) * K + (k0 + lc)]);
        const float4 bv = ld4(&Bw[(size_t)(n0 + lr) * K + (k0 + lc)]);
        __syncthreads();
        As[lc + 0][lr] = av.x; As[lc + 1][lr] = av.y; As[lc + 2][lr] = av.z; As[lc + 3][lr] = av.w;
        Bs[lc + 0][lr] = bv.x; Bs[lc + 1][lr] = bv.y; Bs[lc + 2][lr] = bv.z; Bs[lc + 3][lr] = bv.w;
        __syncthreads();
#pragma unroll
        for (int k = 0; k < BK; ++k) {
            const float4 a4 = ld4(&As[k][ty * 4]);
            const float4 b4 = ld4(&Bs[k][tx * 4]);
            const float ar[4] = {a4.x, a4.y, a4.z, a4.w};
            const float br[4] = {b4.x, b4.y, b4.z, b4.w};
#pragma unroll
            for (int i = 0; i < 4; ++i)
#pragma unroll
                for (int j = 0; j < 4; ++j)
                    acc[i][j] = fmaf(ar[i], br[j], acc[i][j]);
        }
    }
    const int nc = n0 + tx * 4;
    const float4 b1 = ld4(&bias1[nc]);
    const float4 b2 = ld4(&bias2[nc]);
#pragma unroll
    for (int i = 0; i < 4; ++i) {
        const int m = m0 + ty * 4 + i;
        float4 v;
        v.x = acc[i][0] + b1.x + b2.x; v.y = acc[i][1] + b1.y + b2.y;
        v.z = acc[i][2] + b1.z + b2.z; v.w = acc[i][3] + b1.w + b2.w;
        *reinterpret_cast<float4*>(&C[(size_t)m * N + nc]) = v;
    }
}

// ---------------------------------------------------------------------------
// init: tokbuf = 65 step-slots x 1024 packed words; slot 0 preset to SOS
// (packed low32 = 511 -> token 0). ctr[0..63] zeroed (per-m-tile counters).
// ---------------------------------------------------------------------------
__global__ __launch_bounds__(512) void init_buf(
    unsigned long long* __restrict__ tok, unsigned* __restrict__ ctr)
{
    const int i = blockIdx.x * 512 + threadIdx.x; // 0 .. 65*1024-1
    tok[i] = (i < 1024) ? 511ULL : 0ULL;
    if (i < 64) ctr[i] = 0u;
}

// ---------------------------------------------------------------------------
// Fused per-step kernel (launched 65x), 256 blocks x 512 thr, 129KB LDS.
// Kernel t, per block:
//   B-part (t>0): logits(t-1) 16 batch x 128 vocab, W_out/h from L2 (plain);
//     argmax -> device atomicMax into tok(t); EARLY tick on per-m-tile ctr.
//   DMA (t<64): W_hh block slice (64 gate-cols x K=512, hi+lo = 128KB) into
//     LDS via global_load_lds, XOR-swizzled source (chunk = lane ^ (row&7)).
//   A-part (t<64): gates GEMM 128 batch x 64 gate-cols, W from LDS (swizzled
//     ds_read_b128, ~2-way = free), h from L2.
//   spin LATE on the 8 m-tile counters covering this block's batches (slack
//   filled by the A-GEMM), then LSTM cell in registers, plain h/c stores.
// Cross-step coherence = kernel boundaries. tok/ctr only via MALL atomics.
// Numerics: MFMA k-order and cell math identical to r0-r6 (absmax-preserving).
// ---------------------------------------------------------------------------
__global__ __launch_bounds__(512) void decode_step(
    const int t,
    const _Float16* __restrict__ Whh_hi, const _Float16* __restrict__ Whh_lo,
    const _Float16* __restrict__ Wout_hi, const _Float16* __restrict__ Wout_lo,
    const float* __restrict__ Eg, const float* __restrict__ b_out,
    const _Float16* __restrict__ Ah, const _Float16* __restrict__ Al,  // h(t)
    _Float16* __restrict__ Nh, _Float16* __restrict__ Nl,              // h(t+1)
    float* __restrict__ cbuf, float* __restrict__ out,                 // logits(t-1)
    unsigned long long* __restrict__ tok_t, unsigned* __restrict__ ctr)
{
    extern __shared__ __align__(16) char lds[];
    // [0,64K) W_hh hi rows (64 x 1024B, slot-swizzled); [64K,128K) lo;
    // [128K,+1K) argmax reduce buffer
    unsigned long long* sbest = (unsigned long long*)(lds + 131072);

    const int tid = threadIdx.x;
    const int wave = tid >> 6, lane = tid & 63;
    const int lm = lane & 15, kq = lane >> 4;
    const int bid = blockIdx.x;

    // ---- A geometry ----
    const int hc0 = (bid & 31) * 16;
    const int b0 = (bid >> 5) * 128;
    const size_t aOffA = (size_t)(b0 + wave * 16 + lm) * 512 + kq * 8;
    const int bbase = b0 + wave * 16 + kq * 4;
    const int hc = hc0 + lm;

    // ================= B-part: logits(t-1) + argmax -> tok(t) =================
    if (t > 0) {
        const int m0 = (bid >> 2) * 16;
        const int n0v = (bid & 3) * 128;
        const int colB = n0v + wave * 16 + lm;
        const size_t aOffB = (size_t)(m0 + lm) * 512 + kq * 8;
        const size_t bOffB = (size_t)colB * 512 + kq * 8;

        f32x4 aHb = {0.f, 0.f, 0.f, 0.f};
        f32x4 aCb = {0.f, 0.f, 0.f, 0.f};
#pragma unroll
        for (int it = 0; it < 16; ++it) {
            const int k0 = it * 32;
            const half8 ah = *(const half8*)(Ah + aOffB + k0);
            const half8 al = *(const half8*)(Al + aOffB + k0);
            const half8 bh = *(const half8*)(Wout_hi + bOffB + k0);
            const half8 bl = *(const half8*)(Wout_lo + bOffB + k0);
            aHb = __builtin_amdgcn_mfma_f32_16x16x32_f16(ah, bh, aHb, 0, 0, 0);
            aCb = __builtin_amdgcn_mfma_f32_16x16x32_f16(ah, bl, aCb, 0, 0, 0);
            aCb = __builtin_amdgcn_mfma_f32_16x16x32_f16(al, bh, aCb, 0, 0, 0);
        }

        // issue the A-part W_hh DMA now — it drains under the argmax epilogue
        if (t < T_STEPS) {
#pragma unroll
            for (int j = 0; j < 16; ++j) {
                const int idx = wave * 16 + j;       // 0..127
                const int r = idx & 63;              // local gate-col
                const int grow = (r >> 4) * 512 + hc0 + (r & 15);
                const int chunk = lane ^ (r & 7);
                const _Float16* src =
                    (idx < 64 ? Whh_hi : Whh_lo) + (size_t)grow * 512 + chunk * 8;
                GLDS(src, lds + (idx < 64 ? 0 : 65536) + r * 1024);
            }
        }

        const float bo = b_out[colB];
        unsigned long long best[4];
#pragma unroll
        for (int r = 0; r < 4; ++r) {
            const float v = aHb[r] + aCb[r] * (1.f / 2048.f) + bo;
            const int row = m0 + kq * 4 + r;
            __builtin_nontemporal_store(v, &out[(size_t)row * V_SZ + colB]);
            best[r] = pack_vc(v, colB);
        }
#pragma unroll
        for (int r = 0; r < 4; ++r) {
#pragma unroll
            for (int off = 1; off < 16; off <<= 1) {
                const unsigned long long o = __shfl_xor(best[r], off);
                if (o > best[r]) best[r] = o;
            }
        }
        if (lm == 0) {
#pragma unroll
            for (int r = 0; r < 4; ++r)
                sbest[wave * 16 + kq * 4 + r] = best[r];
        }
        __syncthreads();
        if (tid < 16) {
            unsigned long long m = sbest[tid];
#pragma unroll
            for (int w = 1; w < 8; ++w)
                if (sbest[w * 16 + tid] > m) m = sbest[w * 16 + tid];
            atomicMax(&tok_t[m0 + tid], m);
        }
        // wave 0: drain atomicMax, tick this m-tile's counter (target 4)
        if (wave == 0) {
            asm volatile("s_waitcnt vmcnt(0)" ::: "memory");
            if (tid == 0)
                __hip_atomic_fetch_add(&ctr[bid >> 2], 1u, __ATOMIC_RELAXED,
                                       __HIP_MEMORY_SCOPE_AGENT);
        }
    } else {
        // t == 0: no B-part; just issue the DMA
#pragma unroll
        for (int j = 0; j < 16; ++j) {
            const int idx = wave * 16 + j;
            const int r = idx & 63;
            const int grow = (r >> 4) * 512 + hc0 + (r & 15);
            const int chunk = lane ^ (r & 7);
            const _Float16* src =
                (idx < 64 ? Whh_hi : Whh_lo) + (size_t)grow * 512 + chunk * 8;
            GLDS(src, lds + (idx < 64 ? 0 : 65536) + r * 1024);
        }
    }

    // ================= A-part: gates GEMM + spin + cell =================
    if (t < T_STEPS) {
        __syncthreads(); // drains DMA (vmcnt 0 before barrier) -> W in LDS

        f32x4 aH[4] = {{0.f, 0.f, 0.f, 0.f}, {0.f, 0.f, 0.f, 0.f},
                       {0.f, 0.f, 0.f, 0.f}, {0.f, 0.f, 0.f, 0.f}};
        f32x4 aC[4] = {{0.f, 0.f, 0.f, 0.f}, {0.f, 0.f, 0.f, 0.f},
                       {0.f, 0.f, 0.f, 0.f}, {0.f, 0.f, 0.f, 0.f}};
        const int cx = lm & 7;
#pragma unroll
        for (int it = 0; it < 16; ++it) {
            const int k0 = it * 32;
            const half8 ah = *(const half8*)(Ah + aOffA + k0);
            const half8 al = *(const half8*)(Al + aOffA + k0);
            const int s = it * 4 + kq;
            const int so = (((s & 7) ^ cx) | (s & ~7)) * 16;
            half8 bh[4], bl[4];
#pragma unroll
            for (int gn = 0; gn < 4; ++gn) {
                const int rb = (gn * 16 + lm) * 1024;
                bh[gn] = *(const half8*)(lds + rb + so);
                bl[gn] = *(const half8*)(lds + 65536 + rb + so);
            }
#pragma unroll
            for (int gn = 0; gn < 4; ++gn)
                aH[gn] = __builtin_amdgcn_mfma_f32_16x16x32_f16(ah, bh[gn], aH[gn], 0, 0, 0);
#pragma unroll
            for (int gn = 0; gn < 4; ++gn)
                aC[gn] = __builtin_amdgcn_mfma_f32_16x16x32_f16(ah, bl[gn], aC[gn], 0, 0, 0);
#pragma unroll
            for (int gn = 0; gn < 4; ++gn)
                aC[gn] = __builtin_amdgcn_mfma_f32_16x16x32_f16(al, bh[gn], aC[gn], 0, 0, 0);
        }

        // spin (late): the 8 m-tiles covering batches [b0, b0+128)
        if (t > 0) {
            if (tid < 8) {
                const int mt = (bid >> 5) * 8 + tid;
                while (__hip_atomic_load(&ctr[mt], __ATOMIC_RELAXED,
                                         __HIP_MEMORY_SCOPE_AGENT) < 4u) {
                    __builtin_amdgcn_s_sleep(2);
                }
            }
            __syncthreads();
        }

        // cell: lane (lm,kq) holds gates i,f,g,o for batches bbase+r, col hc
#pragma unroll
        for (int r = 0; r < 4; ++r) {
            const int bb = bbase + r;
            const unsigned long long pk = ld_u64_coh(&tok_t[bb]);
            const int tk = 511 - (int)(unsigned)(pk & 0xFFFFFFFFu);
            const float* eg = Eg + (size_t)tk * G_SZ + hc;
            const float iv = aH[0][r] + aC[0][r] * (1.f / 2048.f) + eg[0];
            const float fv = aH[1][r] + aC[1][r] * (1.f / 2048.f) + eg[512];
            const float gv = aH[2][r] + aC[2][r] * (1.f / 2048.f) + eg[1024];
            const float ov = aH[3][r] + aC[3][r] * (1.f / 2048.f) + eg[1536];
            const size_t ci = (size_t)bb * 512 + hc;
            const float cc = cbuf[ci];
            const float cn = sigf(fv) * cc + sigf(iv) * tanhf(gv);
            const float hn = sigf(ov) * tanhf(cn);
            cbuf[ci] = cn;
            const _Float16 hi = (_Float16)hn;
            const _Float16 lo = (_Float16)((hn - (float)hi) * 2048.f);
            Nh[ci] = hi;
            Nl[ci] = lo;
        }
    }
}

// ---------------------------------------------------------------------------
extern "C" void kernel_launch(void* const* d_in, const int* in_sizes, int n_in,
                              void* d_out, int out_size, void* d_ws, size_t ws_size,
                              hipStream_t stream)
{
    const float* enc_h = (const float*)d_in[2];
    const float* enc_c = (const float*)d_in[3];
    const float* emb   = (const float*)d_in[4];
    const float* W_ih  = (const float*)d_in[5];
    const float* W_hh  = (const float*)d_in[6];
    const float* b_ih  = (const float*)d_in[7];
    const float* b_hh  = (const float*)d_in[8];
    const float* W_out = (const float*)d_in[9];
    const float* b_out = (const float*)d_in[10];
    float* out = (float*)d_out;

    // workspace layout
    char* ws = (char*)d_ws;
    _Float16* Whh_hi  = (_Float16*)(ws);                          // 2 MB
    _Float16* Whh_lo  = (_Float16*)(ws + (2u << 20));             // 2 MB
    _Float16* Wout_hi = (_Float16*)(ws + (4u << 20));             // 0.5 MB
    _Float16* Wout_lo = (_Float16*)(ws + (4u << 20) + (512u << 10));
    _Float16* Hhi0 = (_Float16*)(ws + (5u << 20));
    _Float16* Hlo0 = (_Float16*)(ws + (6u << 20));
    _Float16* Hhi1 = (_Float16*)(ws + (7u << 20));
    _Float16* Hlo1 = (_Float16*)(ws + (8u << 20));
    float* cbuf = (float*)(ws + (9u << 20));                      // 2 MB
    float* Eg   = (float*)(ws + (11u << 20));                     // 4 MB
    unsigned long long* tokbuf = (unsigned long long*)(ws + (15u << 20)); // 65*8 KB
    unsigned* ctr = (unsigned*)(ws + (15u << 20) + (544u << 10)); // 64 u32

    const dim3 blk256(256);
    constexpr unsigned DYN_LDS = 131072 + 1024;

    static bool attr_done = false;
    if (!attr_done) {
        (void)hipFuncSetAttribute((const void*)decode_step,
                                  hipFuncAttributeMaxDynamicSharedMemorySize,
                                  (int)DYN_LDS);
        attr_done = true;
    }

    // one-time conversions + init
    cvt_pair<<<(G_SZ * H_SZ) / 1024, blk256, 0, stream>>>(W_hh, Whh_hi, Whh_lo);
    cvt_pair<<<(V_SZ * H_SZ) / 1024, blk256, 0, stream>>>(W_out, Wout_hi, Wout_lo);
    cvt_pair<<<(B_SZ * H_SZ) / 1024, blk256, 0, stream>>>(enc_h, Hhi0, Hlo0);
    hipMemcpyAsync(cbuf, enc_c, (size_t)B_SZ * H_SZ * 4, hipMemcpyDeviceToDevice, stream);
    init_buf<<<(65 * 1024) / 512, dim3(512), 0, stream>>>(tokbuf, ctr);

    // E_gates = emb @ W_ih^T + (b_ih + b_hh)   [V x 4H], fp32, once
    gemm_nt_f32<<<dim3(G_SZ / 64, V_SZ / 64), blk256, 0, stream>>>(
        emb, W_ih, Eg, V_SZ, G_SZ, H_SZ, b_ih, b_hh);

    // 65 fused step kernels: kernel t = logits(t-1)+argmax + gates/cell(t)
    for (int t = 0; t <= T_STEPS; ++t) {
        const int cur = t & 1;
        decode_step<<<NBLK, dim3(512), DYN_LDS, stream>>>(
            t, Whh_hi, Whh_lo, Wout_hi, Wout_lo, Eg, b_out,
            cur ? Hhi1 : Hhi0, cur ? Hlo1 : Hlo0,
            cur ? Hhi0 : Hhi1, cur ? Hlo0 : Hlo1,
            cbuf,
            (t > 0) ? out + (size_t)(t - 1) * B_SZ * V_SZ : out,
            tokbuf + (size_t)t * B_SZ, ctr);
    }
}